// Round 3
// baseline (336.751 us; speedup 1.0000x reference)
//
#include <hip/hip_runtime.h>
#include <hip/hip_fp16.h>
#include <math.h>

#define NSLOPE 0.2f
#define LOG2E  1.44269504f

typedef _Float16 half8 __attribute__((ext_vector_type(8)));
typedef float floatx4 __attribute__((ext_vector_type(4)));
typedef float floatx2 __attribute__((ext_vector_type(2)));

// weight = exp2(lrelu(t)) with t pre-scaled by log2(e) upstream.
__device__ __forceinline__ float wcalc(float t) {
    float l = fmaxf(t, NSLOPE * t);
    float r;
    asm("v_exp_f32 %0, %1" : "=v"(r) : "v"(l));
    return r;
}

// acc[c] += w * fp8_e4m3[c] for 8 packed fp8 channels (one uint2 = 8 bytes).
__device__ __forceinline__ void fma8_fp8(float* acc, float w, uint2 v) {
    floatx2 p0 = __builtin_amdgcn_cvt_pk_f32_fp8(v.x, false);
    floatx2 p1 = __builtin_amdgcn_cvt_pk_f32_fp8(v.x, true);
    floatx2 p2 = __builtin_amdgcn_cvt_pk_f32_fp8(v.y, false);
    floatx2 p3 = __builtin_amdgcn_cvt_pk_f32_fp8(v.y, true);
    acc[0] = fmaf(w, p0.x, acc[0]);
    acc[1] = fmaf(w, p0.y, acc[1]);
    acc[2] = fmaf(w, p1.x, acc[2]);
    acc[3] = fmaf(w, p1.y, acc[3]);
    acc[4] = fmaf(w, p2.x, acc[4]);
    acc[5] = fmaf(w, p2.y, acc[5]);
    acc[6] = fmaf(w, p3.x, acc[6]);
    acc[7] = fmaf(w, p3.y, acc[7]);
}

#define MAXB 5632
#define BE   8192

// ---------------------------------------------------------------------------
// PREP combo kernel: independent setup work in ONE dispatch.
// ---------------------------------------------------------------------------
__global__ __launch_bounds__(256)
void prep_kernel(const int* __restrict__ dst, int* __restrict__ bcnt,
                 const float* __restrict__ x, __half* __restrict__ x16, int nx,
                 const float* __restrict__ W1, __half* __restrict__ W1T,
                 const float* __restrict__ W2, __half* __restrict__ W2T,
                 const float* __restrict__ a_src2, const float* __restrict__ a_dst2,
                 float* __restrict__ w2s, float* __restrict__ w2d,
                 int E, int Etot, int nb, int nbA, int ncast, int nt1, int nt2)
{
    __shared__ int hist[512];
    int bid = blockIdx.x;
    int tid = threadIdx.x;

    if (bid < nbA) {
        // ---- bucketA: histogram of dst>>7 ----
        for (int i = tid; i < 512; i += 256) hist[i] = 0;
        __syncthreads();
        for (int e = bid * 256 + tid; e < Etot; e += nbA * 256) {
            int d = (e < E) ? dst[e] : (e - E);
            atomicAdd(&hist[d >> 7], 1);
        }
        __syncthreads();
        for (int i = tid; i < nb; i += 256) {
            int v = hist[i];
            if (v) atomicAdd(&bcnt[i], v);
        }
        return;
    }
    bid -= nbA;
    if (bid < ncast) {
        int i = (bid * 256 + tid) * 4;
        if (i < nx) {
            float4 v = *(const float4*)&x[i];
            __half2 a = __floats2half2_rn(v.x, v.y);
            __half2 b = __floats2half2_rn(v.z, v.w);
            *(uint2*)&x16[i] = make_uint2(*(unsigned*)&a, *(unsigned*)&b);
        }
        return;
    }
    bid -= ncast;
    if (bid < nt1) {
        int idx = bid * 256 + tid;       // 128x128
        int c = idx >> 7, k = idx & 127;
        W1T[(size_t)c * 128 + k] = __float2half(W1[(size_t)k * 128 + c]);
        return;
    }
    bid -= nt1;
    if (bid < nt2) {
        int idx = bid * 256 + tid;       // 256x128
        int c = idx >> 7, k = idx & 127;
        W2T[(size_t)c * 128 + k] = __float2half(W2[(size_t)k * 256 + c]);
        return;
    }
    // ---- w2sd (pre-scaled by log2(e) so agg2 can use raw v_exp_f32) ----
    {
        const float* a = (tid < 128) ? a_src2 : a_dst2;
        int k = tid & 127;
        float acc = 0.f;
        for (int c = 0; c < 256; c += 4) {
            float4 w = *(const float4*)&W2[(size_t)k * 256 + c];
            float4 av = *(const float4*)&a[c];
            acc = fmaf(w.x, av.x, fmaf(w.y, av.y, fmaf(w.z, av.z, fmaf(w.w, av.w, acc))));
        }
        if (tid < 128) w2s[k] = acc * LOG2E; else w2d[k] = acc * LOG2E;
    }
}

// ---------------------------------------------------------------------------
// scan of bucket counts (1 block)
// ---------------------------------------------------------------------------
__global__ __launch_bounds__(512)
void scanBuckets_kernel(const int* __restrict__ bcnt, int* __restrict__ bbase,
                        int* __restrict__ gcur, int nb, int* __restrict__ offs,
                        int N, int total)
{
    __shared__ int tmp[512];
    int tid = threadIdx.x;
    int v = (tid < nb) ? bcnt[tid] : 0;
    tmp[tid] = v;
    __syncthreads();
    for (int off = 1; off < 512; off <<= 1) {
        int t = (tid >= off) ? tmp[tid - off] : 0;
        __syncthreads();
        tmp[tid] += t;
        __syncthreads();
    }
    if (tid < nb) {
        int e = tmp[tid] - v;
        bbase[tid] = e;
        gcur[tid] = e;
    }
    if (tid == 0) offs[N] = total;
}

// ---------------------------------------------------------------------------
// bucketB: partition edges into bucket-grouped u32 records src | (dst&127)<<16
// ---------------------------------------------------------------------------
__global__ __launch_bounds__(256)
void bucketB_kernel(const int* __restrict__ src, const int* __restrict__ dst,
                    int* __restrict__ gcur, unsigned* __restrict__ eout,
                    int E, int Etot, int nb)
{
    __shared__ int hist[512];
    __shared__ int res[512];
    __shared__ int lcur[512];
    int tid = threadIdx.x;
    int e0 = blockIdx.x * BE;
    int e1 = min(e0 + BE, Etot);

    for (int i = tid; i < 512; i += 256) hist[i] = 0;
    __syncthreads();
    for (int e = e0 + tid; e < e1; e += 256) {
        int d = (e < E) ? dst[e] : (e - E);
        atomicAdd(&hist[d >> 7], 1);
    }
    __syncthreads();
    for (int i = tid; i < nb; i += 256) {
        int h = hist[i];
        res[i] = h ? atomicAdd(&gcur[i], h) : 0;
        lcur[i] = 0;
    }
    __syncthreads();
    for (int e = e0 + tid; e < e1; e += 256) {
        int s, d;
        if (e < E) { s = src[e]; d = dst[e]; }
        else       { s = e - E; d = s; }
        int b = d >> 7;
        int p = res[b] + atomicAdd(&lcur[b], 1);
        eout[p] = (unsigned)s | ((unsigned)(d & 127) << 16);
    }
}

// ---------------------------------------------------------------------------
// COMBO kernel: bucketC (in-LDS sub-CSR) for blocks [0,nb); gemm1 (MFMA) after.
// gemm1 writes h1 as TWO fp8 half-channel tables h1A/h1B ([N][64] each).
// ---------------------------------------------------------------------------
__global__ __launch_bounds__(256)
void combo_kernel(const unsigned* __restrict__ eout, const int* __restrict__ bbase,
                  const int* __restrict__ bcnt, unsigned short* __restrict__ csr,
                  int* __restrict__ offs, int N, int nb,
                  const __half* __restrict__ A16, const __half* __restrict__ W1T,
                  const float* __restrict__ a_src, const float* __restrict__ a_dst,
                  unsigned char* __restrict__ h1A, unsigned char* __restrict__ h1B,
                  float* __restrict__ al_src, float* __restrict__ al_dst)
{
    __shared__ unsigned eb[MAXB];
    __shared__ unsigned short sbuf[MAXB];
    __shared__ int cnt128[128], cur128[128], sc[128];

    int tid = threadIdx.x;
    if ((int)blockIdx.x < nb) {
        // ---------------- bucketC ----------------
        int b = blockIdx.x;
        int ebase = bbase[b];
        int ecnt = bcnt[b];
        int n0 = b << 7;
        int ncount = min(128, N - n0);

        if (tid < 128) cnt128[tid] = 0;
        for (int i = tid; i < ecnt; i += 256) eb[i] = eout[ebase + i];
        __syncthreads();
        for (int i = tid; i < ecnt; i += 256) atomicAdd(&cnt128[eb[i] >> 16], 1);
        __syncthreads();
        if (tid < 128) sc[tid] = cnt128[tid];
        __syncthreads();
        for (int off = 1; off < 128; off <<= 1) {
            int t = (tid >= off && tid < 128) ? sc[tid - off] : 0;
            __syncthreads();
            if (tid < 128) sc[tid] += t;
            __syncthreads();
        }
        if (tid < 128) {
            int excl = sc[tid] - cnt128[tid];
            cur128[tid] = excl;
            if (tid < ncount) offs[n0 + tid] = ebase + excl;
        }
        __syncthreads();
        for (int i = tid; i < ecnt; i += 256) {
            unsigned v = eb[i];
            int p = atomicAdd(&cur128[v >> 16], 1);
            sbuf[p] = (unsigned short)(v & 0xFFFFu);
        }
        __syncthreads();
        for (int i = tid; i < ecnt; i += 256) csr[ebase + i] = sbuf[i];
        return;
    }

    // ---------------- gemm1 (MFMA) ----------------
    int gb = blockIdx.x - nb;
    int M = N;
    int wave = tid >> 6, lane = tid & 63;
    int lr = lane & 15, q = lane >> 4;
    int r0 = gb * 32 + (wave >> 1) * 16;
    int wcol = (wave & 1) * 64;
    unsigned char* hT = (wave & 1) ? h1B : h1A;

    int arow = min(r0 + lr, M - 1);
    const uint4* Arow = (const uint4*)A16 + (size_t)arow * 16;
    half8 a[4];
#pragma unroll
    for (int kb = 0; kb < 4; ++kb) {
        union { uint4 u; half8 h; } c;
        c.u = Arow[kb * 4 + q];
        a[kb] = c.h;
    }

    floatx4 acc[4];
    const floatx4 zero = {0.f, 0.f, 0.f, 0.f};
#pragma unroll
    for (int ct = 0; ct < 4; ++ct) acc[ct] = zero;

#pragma unroll
    for (int ct = 0; ct < 4; ++ct) {
        const uint4* Brow = (const uint4*)W1T + (size_t)(wcol + ct * 16 + lr) * 16;
#pragma unroll
        for (int kb = 0; kb < 4; ++kb) {
            union { uint4 u; half8 h; } c;
            c.u = Brow[kb * 4 + q];
            acc[ct] = __builtin_amdgcn_mfma_f32_16x16x32_f16(a[kb], c.h, acc[ct], 0, 0, 0);
        }
    }

#pragma unroll
    for (int ct = 0; ct < 4; ++ct) {
        int colh = ct * 16 + lr;             // column within the half-table
#pragma unroll
        for (int r = 0; r < 4; ++r) {
            int row = r0 + q * 4 + r;
            if (row < M) {
                unsigned pk = __builtin_amdgcn_cvt_pk_fp8_f32(acc[ct][r], acc[ct][r], 0, false);
                hT[(size_t)row * 64 + colh] = (unsigned char)(pk & 0xFF);
            }
        }
    }

    // attention dots, pre-scaled by log2(e) so agg1 uses raw v_exp_f32
    float as[4], ad[4];
#pragma unroll
    for (int ct = 0; ct < 4; ++ct) {
        int col = wcol + ct * 16 + lr;
        as[ct] = a_src[col] * LOG2E;
        ad[ct] = a_dst[col] * LOG2E;
    }
    int hb = wcol >> 5;
#pragma unroll
    for (int r = 0; r < 4; ++r) {
        float psA = acc[0][r] * as[0] + acc[1][r] * as[1];
        float psB = acc[2][r] * as[2] + acc[3][r] * as[3];
        float pdA = acc[0][r] * ad[0] + acc[1][r] * ad[1];
        float pdB = acc[2][r] * ad[2] + acc[3][r] * ad[3];
#pragma unroll
        for (int off = 1; off < 16; off <<= 1) {
            psA += __shfl_xor(psA, off); psB += __shfl_xor(psB, off);
            pdA += __shfl_xor(pdA, off); pdB += __shfl_xor(pdB, off);
        }
        if (lr == 0) {
            int row = r0 + q * 4 + r;
            if (row < M) {
                al_src[(size_t)row * 4 + hb]     = psA;
                al_src[(size_t)row * 4 + hb + 1] = psB;
                al_dst[(size_t)row * 4 + hb]     = pdA;
                al_dst[(size_t)row * 4 + hb + 1] = pdB;
            }
        }
    }
}

// ---------------------------------------------------------------------------
// Layer-2 GEMM (MFMA): out = m16[M,128] @ W2 (via W2T[256,128]) + b2, fp32 out
// ---------------------------------------------------------------------------
__global__ __launch_bounds__(256)
void gemm2_mfma(const __half* __restrict__ A16, const __half* __restrict__ W2T,
                const float* __restrict__ bias, float* __restrict__ out, int M)
{
    int wave = threadIdx.x >> 6, lane = threadIdx.x & 63;
    int lr = lane & 15, q = lane >> 4;
    int r0 = blockIdx.x * 16;
    int c0 = wave * 64;

    int arow = min(r0 + lr, M - 1);
    const uint4* Arow = (const uint4*)A16 + (size_t)arow * 16;
    half8 a[4];
#pragma unroll
    for (int kb = 0; kb < 4; ++kb) {
        union { uint4 u; half8 h; } c;
        c.u = Arow[kb * 4 + q];
        a[kb] = c.h;
    }

    floatx4 acc[4];
    const floatx4 zero = {0.f, 0.f, 0.f, 0.f};
#pragma unroll
    for (int ct = 0; ct < 4; ++ct) acc[ct] = zero;

#pragma unroll
    for (int ct = 0; ct < 4; ++ct) {
        const uint4* Brow = (const uint4*)W2T + (size_t)(c0 + ct * 16 + lr) * 16;
#pragma unroll
        for (int kb = 0; kb < 4; ++kb) {
            union { uint4 u; half8 h; } c;
            c.u = Brow[kb * 4 + q];
            acc[ct] = __builtin_amdgcn_mfma_f32_16x16x32_f16(a[kb], c.h, acc[ct], 0, 0, 0);
        }
    }

#pragma unroll
    for (int ct = 0; ct < 4; ++ct) {
        int col = c0 + ct * 16 + lr;
        float b = bias[col];
#pragma unroll
        for (int r = 0; r < 4; ++r) {
            int row = r0 + q * 4 + r;
            if (row < M) out[(size_t)row * 256 + col] = acc[ct][r] + b;
        }
    }
}

// ---------------------------------------------------------------------------
// Layer-1 aggregation HALF kernel. feat = [N][64] fp8 half-channel table
// (3.2 MB -> fits per-XCD L2). 8 edge slots x 8 channel-group lanes.
// half 0: writes alS2/alD2; half 1: accumulates into them.
// ---------------------------------------------------------------------------
__global__ __launch_bounds__(256)
void agg1_half_kernel(const unsigned char* __restrict__ feat,
                      const unsigned short* __restrict__ csr_src,
                      const int* __restrict__ offs, const float* __restrict__ alS,
                      const float* __restrict__ alD, const float* __restrict__ bias,
                      const float* __restrict__ w2s, const float* __restrict__ w2d,
                      unsigned char* __restrict__ hmidH, float* __restrict__ alS2,
                      float* __restrict__ alD2, int N, int half)
{
    int lane = threadIdx.x & 63;
    int n = blockIdx.x * 4 + (threadIdx.x >> 6);
    if (n >= N) return;

    int lc = lane & 7;       // channel group: channels half*64 + lc*8 .. +7
    int es = lane >> 3;      // edge slot 0..7
    int head = half * 2 + (lc >> 2);

    float aD = alD[(size_t)n * 4 + head];
    int beg = offs[n], end = offs[n + 1];

    float acc0[8] = {0,0,0,0,0,0,0,0}, acc1[8] = {0,0,0,0,0,0,0,0};
    float sw0 = 0.f, sw1 = 0.f;
    const char* fbase = (const char*)feat + lc * 8;
    const float* alSh = alS + head;

    int j = beg + es;
    for (; j + 8 < end; j += 16) {
        int s0 = csr_src[j];
        int s1 = csr_src[j + 8];
        float w0 = wcalc(alSh[(size_t)s0 * 4] + aD);
        float w1 = wcalc(alSh[(size_t)s1 * 4] + aD);
        uint2 f0 = *(const uint2*)(fbase + (size_t)s0 * 64);
        uint2 f1 = *(const uint2*)(fbase + (size_t)s1 * 64);
        fma8_fp8(acc0, w0, f0); sw0 += w0;
        fma8_fp8(acc1, w1, f1); sw1 += w1;
    }
    if (j < end) {
        int s0 = csr_src[j];
        float w0 = wcalc(alSh[(size_t)s0 * 4] + aD);
        uint2 f0 = *(const uint2*)(fbase + (size_t)s0 * 64);
        fma8_fp8(acc0, w0, f0); sw0 += w0;
    }

    float sw = sw0 + sw1;
    sw += __shfl_xor(sw, 8); sw += __shfl_xor(sw, 16); sw += __shfl_xor(sw, 32);
#pragma unroll
    for (int i = 0; i < 8; ++i) {
        acc0[i] += acc1[i];
        acc0[i] += __shfl_xor(acc0[i], 8);
        acc0[i] += __shfl_xor(acc0[i], 16);
        acc0[i] += __shfl_xor(acc0[i], 32);
    }

    if (lane < 8) {
        float inv = 1.f / (sw + 1e-16f);
        int cb = half * 64 + lc * 8;
        float v[8];
#pragma unroll
        for (int i = 0; i < 8; ++i)
            v[i] = fmaxf(fmaf(acc0[i], inv, bias[cb + i]), 0.f);
        unsigned pk0 = __builtin_amdgcn_cvt_pk_fp8_f32(v[0], v[1], 0, false);
        pk0 = __builtin_amdgcn_cvt_pk_fp8_f32(v[2], v[3], pk0, true);
        unsigned pk1 = __builtin_amdgcn_cvt_pk_fp8_f32(v[4], v[5], 0, false);
        pk1 = __builtin_amdgcn_cvt_pk_fp8_f32(v[6], v[7], pk1, true);
        ((uint2*)hmidH)[(size_t)n * 8 + lc] = make_uint2(pk0, pk1);
        float ps = 0.f, pd = 0.f;
#pragma unroll
        for (int i = 0; i < 8; ++i) {
            ps = fmaf(v[i], w2s[cb + i], ps);
            pd = fmaf(v[i], w2d[cb + i], pd);
        }
        ps += __shfl_xor(ps, 1); ps += __shfl_xor(ps, 2); ps += __shfl_xor(ps, 4);
        pd += __shfl_xor(pd, 1); pd += __shfl_xor(pd, 2); pd += __shfl_xor(pd, 4);
        if (lane == 0) {
            if (half == 0) { alS2[n] = ps;          alD2[n] = pd; }
            else           { alS2[n] = alS2[n] + ps; alD2[n] = alD2[n] + pd; }
        }
    }
}

// ---------------------------------------------------------------------------
// Layer-2 aggregation HALF kernel: gathers fp8 [N][64] hmid half-table,
// writes its 64-channel slice of m16 (fp16 [N][128]).
// ---------------------------------------------------------------------------
__global__ __launch_bounds__(256)
void agg2_half_kernel(const unsigned char* __restrict__ feat,
                      const unsigned short* __restrict__ csr_src,
                      const int* __restrict__ offs, const float* __restrict__ alS,
                      const float* __restrict__ alD, __half* __restrict__ m16,
                      int N, int half)
{
    int lane = threadIdx.x & 63;
    int n = blockIdx.x * 4 + (threadIdx.x >> 6);
    if (n >= N) return;

    int lc = lane & 7;
    int es = lane >> 3;

    float aD = alD[n];
    int beg = offs[n], end = offs[n + 1];

    float acc0[8] = {0,0,0,0,0,0,0,0}, acc1[8] = {0,0,0,0,0,0,0,0};
    float sw0 = 0.f, sw1 = 0.f;
    const char* fbase = (const char*)feat + lc * 8;

    int j = beg + es;
    for (; j + 8 < end; j += 16) {
        int s0 = csr_src[j];
        int s1 = csr_src[j + 8];
        float w0 = wcalc(alS[s0] + aD);
        float w1 = wcalc(alS[s1] + aD);
        uint2 f0 = *(const uint2*)(fbase + (size_t)s0 * 64);
        uint2 f1 = *(const uint2*)(fbase + (size_t)s1 * 64);
        fma8_fp8(acc0, w0, f0); sw0 += w0;
        fma8_fp8(acc1, w1, f1); sw1 += w1;
    }
    if (j < end) {
        int s0 = csr_src[j];
        float w0 = wcalc(alS[s0] + aD);
        uint2 f0 = *(const uint2*)(fbase + (size_t)s0 * 64);
        fma8_fp8(acc0, w0, f0); sw0 += w0;
    }

    float sw = sw0 + sw1;
    sw += __shfl_xor(sw, 8); sw += __shfl_xor(sw, 16); sw += __shfl_xor(sw, 32);
#pragma unroll
    for (int i = 0; i < 8; ++i) {
        acc0[i] += acc1[i];
        acc0[i] += __shfl_xor(acc0[i], 8);
        acc0[i] += __shfl_xor(acc0[i], 16);
        acc0[i] += __shfl_xor(acc0[i], 32);
    }

    if (lane < 8) {
        float inv = 1.f / (sw + 1e-16f);
        float v[8];
#pragma unroll
        for (int i = 0; i < 8; ++i) v[i] = acc0[i] * inv;
        __half2 p0 = __floats2half2_rn(v[0], v[1]);
        __half2 p1 = __floats2half2_rn(v[2], v[3]);
        __half2 p2 = __floats2half2_rn(v[4], v[5]);
        __half2 p3 = __floats2half2_rn(v[6], v[7]);
        uint4 pk = make_uint4(*(unsigned*)&p0, *(unsigned*)&p1,
                              *(unsigned*)&p2, *(unsigned*)&p3);
        ((uint4*)m16)[(size_t)n * 16 + half * 8 + lc] = pk;
    }
}

// ---------------------------------------------------------------------------
extern "C" void kernel_launch(void* const* d_in, const int* in_sizes, int n_in,
                              void* d_out, int out_size, void* d_ws, size_t ws_size,
                              hipStream_t stream)
{
    const float* x      = (const float*)d_in[0];
    const int*   ei     = (const int*)d_in[1];
    const float* W1     = (const float*)d_in[2];
    const float* a_src1 = (const float*)d_in[3];
    const float* a_dst1 = (const float*)d_in[4];
    const float* b1     = (const float*)d_in[5];
    const float* W2     = (const float*)d_in[6];
    const float* a_src2 = (const float*)d_in[7];
    const float* a_dst2 = (const float*)d_in[8];
    const float* b2     = (const float*)d_in[9];

    const int N    = in_sizes[0] / 128;
    const int E    = in_sizes[1] / 2;
    const int Etot = E + N;
    const int* src = ei;
    const int* dst = ei + E;
    const int nb   = (N + 127) >> 7;

    char* ws = (char*)d_ws;
    size_t off = 0;
    auto carve = [&](size_t bytes) -> void* {
        void* p = ws + off;
        off += (bytes + 255) & ~(size_t)255;
        return p;
    };
    __half*  x16  = (__half*)carve((size_t)N * 128 * 2);
    unsigned char* h1A   = (unsigned char*)carve((size_t)N * 64);   // fp8, ch 0-63
    unsigned char* h1B   = (unsigned char*)carve((size_t)N * 64);   // fp8, ch 64-127
    unsigned char* hmidA = (unsigned char*)carve((size_t)N * 64);   // fp8, ch 0-63
    unsigned char* hmidB = (unsigned char*)carve((size_t)N * 64);   // fp8, ch 64-127
    __half*  m16  = (__half*)carve((size_t)N * 128 * 2);
    __half*  W1T  = (__half*)carve(128 * 128 * 2);
    __half*  W2T  = (__half*)carve(256 * 128 * 2);
    float*   alS1 = (float*)carve((size_t)N * 4 * 4);
    float*   alD1 = (float*)carve((size_t)N * 4 * 4);
    float*   alS2 = (float*)carve((size_t)N * 4);
    float*   alD2 = (float*)carve((size_t)N * 4);
    float*   w2s  = (float*)carve(128 * 4);
    float*   w2d  = (float*)carve(128 * 4);
    int*     offs = (int*)carve((size_t)(N + 1) * 4);
    int*     bcnt = (int*)carve(512 * 4);
    int*     bbas = (int*)carve(512 * 4);
    int*     gcur = (int*)carve(512 * 4);
    unsigned* eout = (unsigned*)carve((size_t)Etot * 4);
    unsigned short* csr = (unsigned short*)carve((size_t)Etot * 2);
    (void)ws_size; (void)n_in; (void)out_size;

    const int TB = 256;
    const int agrid = (N + 3) / 4;     // wave-per-node agg blocks
    const int g1grid = (N + 31) / 32;  // gemm1: 32 rows/block
    const int g2grid = (N + 15) / 16;  // gemm2: 16 rows/block
    const int nx = N * 128;

    // prep combo block ranges
    const int nbA   = 512;
    const int ncast = (nx / 4 + TB - 1) / TB;
    const int nt1   = (128 * 128 + TB - 1) / TB;
    const int nt2   = (256 * 128 + TB - 1) / TB;
    const int nprep = nbA + ncast + nt1 + nt2 + 1;

    hipMemsetAsync(bcnt, 0, 512 * 4, stream);

    // 1. prep: bucketA + cast + transposes + w2sd (all independent)
    prep_kernel<<<nprep, TB, 0, stream>>>(dst, bcnt, x, x16, nx, W1, W1T, W2, W2T,
                                          a_src2, a_dst2, w2s, w2d,
                                          E, Etot, nb, nbA, ncast, nt1, nt2);
    // 2. bucket scan
    scanBuckets_kernel<<<1, 512, 0, stream>>>(bcnt, bbas, gcur, nb, offs, N, Etot);
    // 3. bucket partition
    bucketB_kernel<<<(Etot + BE - 1) / BE, TB, 0, stream>>>(src, dst, gcur, eout, E, Etot, nb);
    // 4. combo: bucketC (sub-CSR) + gemm1 (MFMA) — independent of each other
    combo_kernel<<<nb + g1grid, TB, 0, stream>>>(eout, bbas, bcnt, csr, offs, N, nb,
                                                 x16, W1T, a_src1, a_dst1, h1A, h1B, alS1, alD1);
    // 5. layer-1 aggregation, two half-channel passes (each table 3.2 MB -> L2-resident)
    agg1_half_kernel<<<agrid, TB, 0, stream>>>(h1A, csr, offs, alS1, alD1, b1,
                                               w2s, w2d, hmidA, alS2, alD2, N, 0);
    agg1_half_kernel<<<agrid, TB, 0, stream>>>(h1B, csr, offs, alS1, alD1, b1,
                                               w2s, w2d, hmidB, alS2, alD2, N, 1);
    // 6. layer-2 aggregation, two half-channel passes
    agg2_half_kernel<<<agrid, TB, 0, stream>>>(hmidA, csr, offs, alS2, alD2, m16, N, 0);
    agg2_half_kernel<<<agrid, TB, 0, stream>>>(hmidB, csr, offs, alS2, alD2, m16, N, 1);
    // 7. layer-2 GEMM (MFMA) + bias
    gemm2_mfma<<<g2grid, TB, 0, stream>>>(m16, W2T, b2, (float*)d_out, N);
}

// Round 5
// 280.244 us; speedup vs baseline: 1.2016x; 1.2016x over previous
//
#include <hip/hip_runtime.h>
#include <hip/hip_fp16.h>
#include <math.h>

#define NSLOPE 0.2f
#define LOG2E  1.44269504f

typedef _Float16 half8 __attribute__((ext_vector_type(8)));
typedef float floatx4 __attribute__((ext_vector_type(4)));
typedef float floatx2 __attribute__((ext_vector_type(2)));

// weight = exp2(lrelu(t)) with t pre-scaled by log2(e) upstream.
__device__ __forceinline__ float wcalc(float t) {
    float l = fmaxf(t, NSLOPE * t);
    float r;
    asm("v_exp_f32 %0, %1" : "=v"(r) : "v"(l));
    return r;
}

// acc[c] += w * fp8_e4m3[c] for 8 packed fp8 channels (one uint2 = 8 bytes).
__device__ __forceinline__ void fma8_fp8(float* acc, float w, uint2 v) {
    floatx2 p0 = __builtin_amdgcn_cvt_pk_f32_fp8(v.x, false);
    floatx2 p1 = __builtin_amdgcn_cvt_pk_f32_fp8(v.x, true);
    floatx2 p2 = __builtin_amdgcn_cvt_pk_f32_fp8(v.y, false);
    floatx2 p3 = __builtin_amdgcn_cvt_pk_f32_fp8(v.y, true);
    acc[0] = fmaf(w, p0.x, acc[0]);
    acc[1] = fmaf(w, p0.y, acc[1]);
    acc[2] = fmaf(w, p1.x, acc[2]);
    acc[3] = fmaf(w, p1.y, acc[3]);
    acc[4] = fmaf(w, p2.x, acc[4]);
    acc[5] = fmaf(w, p2.y, acc[5]);
    acc[6] = fmaf(w, p3.x, acc[6]);
    acc[7] = fmaf(w, p3.y, acc[7]);
}

#define MAXB 5632
#define BE   8192

// ---------------------------------------------------------------------------
// PREP combo kernel: independent setup work in ONE dispatch.
// ---------------------------------------------------------------------------
__global__ __launch_bounds__(256)
void prep_kernel(const int* __restrict__ dst, int* __restrict__ bcnt,
                 const float* __restrict__ x, __half* __restrict__ x16, int nx,
                 const float* __restrict__ W1, __half* __restrict__ W1T,
                 const float* __restrict__ W2, __half* __restrict__ W2T,
                 const float* __restrict__ a_src2, const float* __restrict__ a_dst2,
                 float* __restrict__ w2s, float* __restrict__ w2d,
                 int E, int Etot, int nb, int nbA, int ncast, int nt1, int nt2)
{
    __shared__ int hist[512];
    int bid = blockIdx.x;
    int tid = threadIdx.x;

    if (bid < nbA) {
        // ---- bucketA: histogram of dst>>7 ----
        for (int i = tid; i < 512; i += 256) hist[i] = 0;
        __syncthreads();
        for (int e = bid * 256 + tid; e < Etot; e += nbA * 256) {
            int d = (e < E) ? dst[e] : (e - E);
            atomicAdd(&hist[d >> 7], 1);
        }
        __syncthreads();
        for (int i = tid; i < nb; i += 256) {
            int v = hist[i];
            if (v) atomicAdd(&bcnt[i], v);
        }
        return;
    }
    bid -= nbA;
    if (bid < ncast) {
        int i = (bid * 256 + tid) * 4;
        if (i < nx) {
            float4 v = *(const float4*)&x[i];
            __half2 a = __floats2half2_rn(v.x, v.y);
            __half2 b = __floats2half2_rn(v.z, v.w);
            *(uint2*)&x16[i] = make_uint2(*(unsigned*)&a, *(unsigned*)&b);
        }
        return;
    }
    bid -= ncast;
    if (bid < nt1) {
        int idx = bid * 256 + tid;       // 128x128
        int c = idx >> 7, k = idx & 127;
        W1T[(size_t)c * 128 + k] = __float2half(W1[(size_t)k * 128 + c]);
        return;
    }
    bid -= nt1;
    if (bid < nt2) {
        int idx = bid * 256 + tid;       // 256x128
        int c = idx >> 7, k = idx & 127;
        W2T[(size_t)c * 128 + k] = __float2half(W2[(size_t)k * 256 + c]);
        return;
    }
    // ---- w2sd (pre-scaled by log2(e) so agg2 can use raw v_exp_f32) ----
    {
        const float* a = (tid < 128) ? a_src2 : a_dst2;
        int k = tid & 127;
        float acc = 0.f;
        for (int c = 0; c < 256; c += 4) {
            float4 w = *(const float4*)&W2[(size_t)k * 256 + c];
            float4 av = *(const float4*)&a[c];
            acc = fmaf(w.x, av.x, fmaf(w.y, av.y, fmaf(w.z, av.z, fmaf(w.w, av.w, acc))));
        }
        if (tid < 128) w2s[k] = acc * LOG2E; else w2d[k] = acc * LOG2E;
    }
}

// ---------------------------------------------------------------------------
// scan of bucket counts (1 block)
// ---------------------------------------------------------------------------
__global__ __launch_bounds__(512)
void scanBuckets_kernel(const int* __restrict__ bcnt, int* __restrict__ bbase,
                        int* __restrict__ gcur, int nb, int* __restrict__ offs,
                        int N, int total)
{
    __shared__ int tmp[512];
    int tid = threadIdx.x;
    int v = (tid < nb) ? bcnt[tid] : 0;
    tmp[tid] = v;
    __syncthreads();
    for (int off = 1; off < 512; off <<= 1) {
        int t = (tid >= off) ? tmp[tid - off] : 0;
        __syncthreads();
        tmp[tid] += t;
        __syncthreads();
    }
    if (tid < nb) {
        int e = tmp[tid] - v;
        bbase[tid] = e;
        gcur[tid] = e;
    }
    if (tid == 0) offs[N] = total;
}

// ---------------------------------------------------------------------------
// bucketB: partition edges into bucket-grouped u32 records src | (dst&127)<<16
// ---------------------------------------------------------------------------
__global__ __launch_bounds__(256)
void bucketB_kernel(const int* __restrict__ src, const int* __restrict__ dst,
                    int* __restrict__ gcur, unsigned* __restrict__ eout,
                    int E, int Etot, int nb)
{
    __shared__ int hist[512];
    __shared__ int res[512];
    __shared__ int lcur[512];
    int tid = threadIdx.x;
    int e0 = blockIdx.x * BE;
    int e1 = min(e0 + BE, Etot);

    for (int i = tid; i < 512; i += 256) hist[i] = 0;
    __syncthreads();
    for (int e = e0 + tid; e < e1; e += 256) {
        int d = (e < E) ? dst[e] : (e - E);
        atomicAdd(&hist[d >> 7], 1);
    }
    __syncthreads();
    for (int i = tid; i < nb; i += 256) {
        int h = hist[i];
        res[i] = h ? atomicAdd(&gcur[i], h) : 0;
        lcur[i] = 0;
    }
    __syncthreads();
    for (int e = e0 + tid; e < e1; e += 256) {
        int s, d;
        if (e < E) { s = src[e]; d = dst[e]; }
        else       { s = e - E; d = s; }
        int b = d >> 7;
        int p = res[b] + atomicAdd(&lcur[b], 1);
        eout[p] = (unsigned)s | ((unsigned)(d & 127) << 16);
    }
}

// ---------------------------------------------------------------------------
// COMBO kernel: bucketC (in-LDS sub-CSR) for blocks [0,nb); gemm1 (MFMA) after.
// gemm1 writes h1 as FP8 e4m3 ([N][128], one 128B line per row).
// ---------------------------------------------------------------------------
__global__ __launch_bounds__(256)
void combo_kernel(const unsigned* __restrict__ eout, const int* __restrict__ bbase,
                  const int* __restrict__ bcnt, unsigned short* __restrict__ csr,
                  int* __restrict__ offs, int N, int nb,
                  const __half* __restrict__ A16, const __half* __restrict__ W1T,
                  const float* __restrict__ a_src, const float* __restrict__ a_dst,
                  unsigned char* __restrict__ h1, float* __restrict__ al_src,
                  float* __restrict__ al_dst)
{
    __shared__ unsigned eb[MAXB];
    __shared__ unsigned short sbuf[MAXB];
    __shared__ int cnt128[128], cur128[128], sc[128];

    int tid = threadIdx.x;
    if ((int)blockIdx.x < nb) {
        // ---------------- bucketC ----------------
        int b = blockIdx.x;
        int ebase = bbase[b];
        int ecnt = bcnt[b];
        int n0 = b << 7;
        int ncount = min(128, N - n0);

        if (tid < 128) cnt128[tid] = 0;
        for (int i = tid; i < ecnt; i += 256) eb[i] = eout[ebase + i];
        __syncthreads();
        for (int i = tid; i < ecnt; i += 256) atomicAdd(&cnt128[eb[i] >> 16], 1);
        __syncthreads();
        if (tid < 128) sc[tid] = cnt128[tid];
        __syncthreads();
        for (int off = 1; off < 128; off <<= 1) {
            int t = (tid >= off && tid < 128) ? sc[tid - off] : 0;
            __syncthreads();
            if (tid < 128) sc[tid] += t;
            __syncthreads();
        }
        if (tid < 128) {
            int excl = sc[tid] - cnt128[tid];
            cur128[tid] = excl;
            if (tid < ncount) offs[n0 + tid] = ebase + excl;
        }
        __syncthreads();
        for (int i = tid; i < ecnt; i += 256) {
            unsigned v = eb[i];
            int p = atomicAdd(&cur128[v >> 16], 1);
            sbuf[p] = (unsigned short)(v & 0xFFFFu);
        }
        __syncthreads();
        for (int i = tid; i < ecnt; i += 256) csr[ebase + i] = sbuf[i];
        return;
    }

    // ---------------- gemm1 (MFMA) ----------------
    int gb = blockIdx.x - nb;
    int M = N;
    int wave = tid >> 6, lane = tid & 63;
    int lr = lane & 15, q = lane >> 4;
    int r0 = gb * 32 + (wave >> 1) * 16;
    int wcol = (wave & 1) * 64;

    int arow = min(r0 + lr, M - 1);
    const uint4* Arow = (const uint4*)A16 + (size_t)arow * 16;
    half8 a[4];
#pragma unroll
    for (int kb = 0; kb < 4; ++kb) {
        union { uint4 u; half8 h; } c;
        c.u = Arow[kb * 4 + q];
        a[kb] = c.h;
    }

    floatx4 acc[4];
    const floatx4 zero = {0.f, 0.f, 0.f, 0.f};
#pragma unroll
    for (int ct = 0; ct < 4; ++ct) acc[ct] = zero;

#pragma unroll
    for (int ct = 0; ct < 4; ++ct) {
        const uint4* Brow = (const uint4*)W1T + (size_t)(wcol + ct * 16 + lr) * 16;
#pragma unroll
        for (int kb = 0; kb < 4; ++kb) {
            union { uint4 u; half8 h; } c;
            c.u = Brow[kb * 4 + q];
            acc[ct] = __builtin_amdgcn_mfma_f32_16x16x32_f16(a[kb], c.h, acc[ct], 0, 0, 0);
        }
    }

#pragma unroll
    for (int ct = 0; ct < 4; ++ct) {
        int col = wcol + ct * 16 + lr;
#pragma unroll
        for (int r = 0; r < 4; ++r) {
            int row = r0 + q * 4 + r;
            if (row < M) {
                unsigned pk = __builtin_amdgcn_cvt_pk_fp8_f32(acc[ct][r], acc[ct][r], 0, false);
                h1[(size_t)row * 128 + col] = (unsigned char)(pk & 0xFF);
            }
        }
    }

    // attention dots, pre-scaled by log2(e) so agg1 uses raw v_exp_f32
    float as[4], ad[4];
#pragma unroll
    for (int ct = 0; ct < 4; ++ct) {
        int col = wcol + ct * 16 + lr;
        as[ct] = a_src[col] * LOG2E;
        ad[ct] = a_dst[col] * LOG2E;
    }
    int hb = wcol >> 5;
#pragma unroll
    for (int r = 0; r < 4; ++r) {
        float psA = acc[0][r] * as[0] + acc[1][r] * as[1];
        float psB = acc[2][r] * as[2] + acc[3][r] * as[3];
        float pdA = acc[0][r] * ad[0] + acc[1][r] * ad[1];
        float pdB = acc[2][r] * ad[2] + acc[3][r] * ad[3];
#pragma unroll
        for (int off = 1; off < 16; off <<= 1) {
            psA += __shfl_xor(psA, off); psB += __shfl_xor(psB, off);
            pdA += __shfl_xor(pdA, off); pdB += __shfl_xor(pdB, off);
        }
        if (lr == 0) {
            int row = r0 + q * 4 + r;
            if (row < M) {
                al_src[(size_t)row * 4 + hb]     = psA;
                al_src[(size_t)row * 4 + hb + 1] = psB;
                al_dst[(size_t)row * 4 + hb]     = pdA;
                al_dst[(size_t)row * 4 + hb + 1] = pdB;
            }
        }
    }
}

// ---------------------------------------------------------------------------
// Layer-2 GEMM (MFMA): out = m16[M,128] @ W2 (via W2T[256,128]) + b2, fp32 out
// ---------------------------------------------------------------------------
__global__ __launch_bounds__(256)
void gemm2_mfma(const __half* __restrict__ A16, const __half* __restrict__ W2T,
                const float* __restrict__ bias, float* __restrict__ out, int M)
{
    int wave = threadIdx.x >> 6, lane = threadIdx.x & 63;
    int lr = lane & 15, q = lane >> 4;
    int r0 = blockIdx.x * 16;
    int c0 = wave * 64;

    int arow = min(r0 + lr, M - 1);
    const uint4* Arow = (const uint4*)A16 + (size_t)arow * 16;
    half8 a[4];
#pragma unroll
    for (int kb = 0; kb < 4; ++kb) {
        union { uint4 u; half8 h; } c;
        c.u = Arow[kb * 4 + q];
        a[kb] = c.h;
    }

    floatx4 acc[4];
    const floatx4 zero = {0.f, 0.f, 0.f, 0.f};
#pragma unroll
    for (int ct = 0; ct < 4; ++ct) acc[ct] = zero;

#pragma unroll
    for (int ct = 0; ct < 4; ++ct) {
        const uint4* Brow = (const uint4*)W2T + (size_t)(c0 + ct * 16 + lr) * 16;
#pragma unroll
        for (int kb = 0; kb < 4; ++kb) {
            union { uint4 u; half8 h; } c;
            c.u = Brow[kb * 4 + q];
            acc[ct] = __builtin_amdgcn_mfma_f32_16x16x32_f16(a[kb], c.h, acc[ct], 0, 0, 0);
        }
    }

#pragma unroll
    for (int ct = 0; ct < 4; ++ct) {
        int col = c0 + ct * 16 + lr;
        float b = bias[col];
#pragma unroll
        for (int r = 0; r < 4; ++r) {
            int row = r0 + q * 4 + r;
            if (row < M) out[(size_t)row * 256 + col] = acc[ct][r] + b;
        }
    }
}

// ---------------------------------------------------------------------------
// Layer-1 aggregation, WAVE-PER-NODE. feat fp8 [N][128]; hmid written fp8.
// ---------------------------------------------------------------------------
__global__ __launch_bounds__(256)
void agg1_kernel(const unsigned char* __restrict__ feat, const unsigned short* __restrict__ csr_src,
                 const int* __restrict__ offs, const float* __restrict__ alS,
                 const float* __restrict__ alD, const float* __restrict__ bias,
                 const float* __restrict__ w2s, const float* __restrict__ w2d,
                 unsigned char* __restrict__ hmid, float* __restrict__ alS2,
                 float* __restrict__ alD2, int N)
{
    int lane = threadIdx.x & 63;
    int n = blockIdx.x * 4 + (threadIdx.x >> 6);
    if (n >= N) return;

    int lc = lane & 15;      // channel group: channels lc*8 .. lc*8+7
    int es = lane >> 4;      // edge slot 0..3
    int h = lc >> 2;         // head of this lane's channels

    float aD = alD[(size_t)n * 4 + h];
    int beg = offs[n], end = offs[n + 1];

    float acc0[8] = {0,0,0,0,0,0,0,0}, acc1[8] = {0,0,0,0,0,0,0,0};
    float sw0 = 0.f, sw1 = 0.f;
    const char* fbase = (const char*)feat + lc * 8;
    const float* alSh = alS + h;

    int j = beg + es;
    for (; j + 12 < end; j += 16) {
        int s0 = csr_src[j];
        int s1 = csr_src[j + 4];
        int s2 = csr_src[j + 8];
        int s3 = csr_src[j + 12];
        float w0 = wcalc(alSh[(size_t)s0 * 4] + aD);
        float w1 = wcalc(alSh[(size_t)s1 * 4] + aD);
        float w2 = wcalc(alSh[(size_t)s2 * 4] + aD);
        float w3 = wcalc(alSh[(size_t)s3 * 4] + aD);
        uint2 f0 = *(const uint2*)(fbase + (size_t)s0 * 128);
        uint2 f1 = *(const uint2*)(fbase + (size_t)s1 * 128);
        uint2 f2 = *(const uint2*)(fbase + (size_t)s2 * 128);
        uint2 f3 = *(const uint2*)(fbase + (size_t)s3 * 128);
        fma8_fp8(acc0, w0, f0); sw0 += w0;
        fma8_fp8(acc1, w1, f1); sw1 += w1;
        fma8_fp8(acc0, w2, f2); sw0 += w2;
        fma8_fp8(acc1, w3, f3); sw1 += w3;
    }
    for (; j < end; j += 4) {
        int s0 = csr_src[j];
        float w0 = wcalc(alSh[(size_t)s0 * 4] + aD);
        uint2 f0 = *(const uint2*)(fbase + (size_t)s0 * 128);
        fma8_fp8(acc0, w0, f0); sw0 += w0;
    }

    float sw = sw0 + sw1;
    sw += __shfl_xor(sw, 16); sw += __shfl_xor(sw, 32);
#pragma unroll
    for (int i = 0; i < 8; ++i) {
        acc0[i] += acc1[i];
        acc0[i] += __shfl_xor(acc0[i], 16);
        acc0[i] += __shfl_xor(acc0[i], 32);
    }

    if (lane < 16) {
        float inv = 1.f / (sw + 1e-16f);
        float v[8];
#pragma unroll
        for (int i = 0; i < 8; ++i)
            v[i] = fmaxf(fmaf(acc0[i], inv, bias[lc * 8 + i]), 0.f);
        unsigned pk0 = __builtin_amdgcn_cvt_pk_fp8_f32(v[0], v[1], 0, false);
        pk0 = __builtin_amdgcn_cvt_pk_fp8_f32(v[2], v[3], pk0, true);
        unsigned pk1 = __builtin_amdgcn_cvt_pk_fp8_f32(v[4], v[5], 0, false);
        pk1 = __builtin_amdgcn_cvt_pk_fp8_f32(v[6], v[7], pk1, true);
        ((uint2*)hmid)[(size_t)n * 16 + lc] = make_uint2(pk0, pk1);
        float ps = 0.f, pd = 0.f;
#pragma unroll
        for (int i = 0; i < 8; ++i) {
            ps = fmaf(v[i], w2s[lc * 8 + i], ps);
            pd = fmaf(v[i], w2d[lc * 8 + i], pd);
        }
        ps += __shfl_xor(ps, 1); ps += __shfl_xor(ps, 2);
        ps += __shfl_xor(ps, 4); ps += __shfl_xor(ps, 8);
        pd += __shfl_xor(pd, 1); pd += __shfl_xor(pd, 2);
        pd += __shfl_xor(pd, 4); pd += __shfl_xor(pd, 8);
        if (lane == 0) { alS2[n] = ps; alD2[n] = pd; }
    }
}

// ---------------------------------------------------------------------------
// Layer-2 aggregation, WAVE-PER-NODE. feat (hmid) fp8 [N][128]; m16 fp16 out.
// ---------------------------------------------------------------------------
__global__ __launch_bounds__(256)
void agg2_kernel(const unsigned char* __restrict__ feat, const unsigned short* __restrict__ csr_src,
                 const int* __restrict__ offs, const float* __restrict__ alS,
                 const float* __restrict__ alD, __half* __restrict__ m16, int N)
{
    int lane = threadIdx.x & 63;
    int n = blockIdx.x * 4 + (threadIdx.x >> 6);
    if (n >= N) return;

    int lc = lane & 15;
    int es = lane >> 4;

    float aD = alD[n];
    int beg = offs[n], end = offs[n + 1];

    float acc0[8] = {0,0,0,0,0,0,0,0}, acc1[8] = {0,0,0,0,0,0,0,0};
    float sw0 = 0.f, sw1 = 0.f;
    const char* fbase = (const char*)feat + lc * 8;

    int j = beg + es;
    for (; j + 12 < end; j += 16) {
        int s0 = csr_src[j];
        int s1 = csr_src[j + 4];
        int s2 = csr_src[j + 8];
        int s3 = csr_src[j + 12];
        float w0 = wcalc(alS[s0] + aD);
        float w1 = wcalc(alS[s1] + aD);
        float w2 = wcalc(alS[s2] + aD);
        float w3 = wcalc(alS[s3] + aD);
        uint2 f0 = *(const uint2*)(fbase + (size_t)s0 * 128);
        uint2 f1 = *(const uint2*)(fbase + (size_t)s1 * 128);
        uint2 f2 = *(const uint2*)(fbase + (size_t)s2 * 128);
        uint2 f3 = *(const uint2*)(fbase + (size_t)s3 * 128);
        fma8_fp8(acc0, w0, f0); sw0 += w0;
        fma8_fp8(acc1, w1, f1); sw1 += w1;
        fma8_fp8(acc0, w2, f2); sw0 += w2;
        fma8_fp8(acc1, w3, f3); sw1 += w3;
    }
    for (; j < end; j += 4) {
        int s0 = csr_src[j];
        float w0 = wcalc(alS[s0] + aD);
        uint2 f0 = *(const uint2*)(fbase + (size_t)s0 * 128);
        fma8_fp8(acc0, w0, f0); sw0 += w0;
    }

    float sw = sw0 + sw1;
    sw += __shfl_xor(sw, 16); sw += __shfl_xor(sw, 32);
#pragma unroll
    for (int i = 0; i < 8; ++i) {
        acc0[i] += acc1[i];
        acc0[i] += __shfl_xor(acc0[i], 16);
        acc0[i] += __shfl_xor(acc0[i], 32);
    }

    if (lane < 16) {
        float inv = 1.f / (sw + 1e-16f);
        float v[8];
#pragma unroll
        for (int i = 0; i < 8; ++i) v[i] = acc0[i] * inv;
        __half2 p0 = __floats2half2_rn(v[0], v[1]);
        __half2 p1 = __floats2half2_rn(v[2], v[3]);
        __half2 p2 = __floats2half2_rn(v[4], v[5]);
        __half2 p3 = __floats2half2_rn(v[6], v[7]);
        uint4 pk = make_uint4(*(unsigned*)&p0, *(unsigned*)&p1,
                              *(unsigned*)&p2, *(unsigned*)&p3);
        ((uint4*)m16)[(size_t)n * 16 + lc] = pk;
    }
}

// ---------------------------------------------------------------------------
extern "C" void kernel_launch(void* const* d_in, const int* in_sizes, int n_in,
                              void* d_out, int out_size, void* d_ws, size_t ws_size,
                              hipStream_t stream)
{
    const float* x      = (const float*)d_in[0];
    const int*   ei     = (const int*)d_in[1];
    const float* W1     = (const float*)d_in[2];
    const float* a_src1 = (const float*)d_in[3];
    const float* a_dst1 = (const float*)d_in[4];
    const float* b1     = (const float*)d_in[5];
    const float* W2     = (const float*)d_in[6];
    const float* a_src2 = (const float*)d_in[7];
    const float* a_dst2 = (const float*)d_in[8];
    const float* b2     = (const float*)d_in[9];

    const int N    = in_sizes[0] / 128;
    const int E    = in_sizes[1] / 2;
    const int Etot = E + N;
    const int* src = ei;
    const int* dst = ei + E;
    const int nb   = (N + 127) >> 7;

    char* ws = (char*)d_ws;
    size_t off = 0;
    auto carve = [&](size_t bytes) -> void* {
        void* p = ws + off;
        off += (bytes + 255) & ~(size_t)255;
        return p;
    };
    __half*  x16  = (__half*)carve((size_t)N * 128 * 2);
    unsigned char* h1   = (unsigned char*)carve((size_t)N * 128);  // fp8 e4m3
    unsigned char* hmid = (unsigned char*)carve((size_t)N * 128);  // fp8 e4m3
    __half*  m16  = (__half*)carve((size_t)N * 128 * 2);
    __half*  W1T  = (__half*)carve(128 * 128 * 2);
    __half*  W2T  = (__half*)carve(256 * 128 * 2);
    float*   alS1 = (float*)carve((size_t)N * 4 * 4);
    float*   alD1 = (float*)carve((size_t)N * 4 * 4);
    float*   alS2 = (float*)carve((size_t)N * 4);
    float*   alD2 = (float*)carve((size_t)N * 4);
    float*   w2s  = (float*)carve(128 * 4);
    float*   w2d  = (float*)carve(128 * 4);
    int*     offs = (int*)carve((size_t)(N + 1) * 4);
    int*     bcnt = (int*)carve(512 * 4);
    int*     bbas = (int*)carve(512 * 4);
    int*     gcur = (int*)carve(512 * 4);
    unsigned* eout = (unsigned*)carve((size_t)Etot * 4);
    unsigned short* csr = (unsigned short*)carve((size_t)Etot * 2);
    (void)ws_size; (void)n_in; (void)out_size;

    const int TB = 256;
    const int agrid = (N + 3) / 4;     // wave-per-node agg blocks
    const int g1grid = (N + 31) / 32;  // gemm1: 32 rows/block
    const int g2grid = (N + 15) / 16;  // gemm2: 16 rows/block
    const int nx = N * 128;

    // prep combo block ranges
    const int nbA   = 512;
    const int ncast = (nx / 4 + TB - 1) / TB;
    const int nt1   = (128 * 128 + TB - 1) / TB;
    const int nt2   = (256 * 128 + TB - 1) / TB;
    const int nprep = nbA + ncast + nt1 + nt2 + 1;

    hipMemsetAsync(bcnt, 0, 512 * 4, stream);

    // 1. prep: bucketA + cast + transposes + w2sd (all independent)
    prep_kernel<<<nprep, TB, 0, stream>>>(dst, bcnt, x, x16, nx, W1, W1T, W2, W2T,
                                          a_src2, a_dst2, w2s, w2d,
                                          E, Etot, nb, nbA, ncast, nt1, nt2);
    // 2. bucket scan
    scanBuckets_kernel<<<1, 512, 0, stream>>>(bcnt, bbas, gcur, nb, offs, N, Etot);
    // 3. bucket partition
    bucketB_kernel<<<(Etot + BE - 1) / BE, TB, 0, stream>>>(src, dst, gcur, eout, E, Etot, nb);
    // 4. combo: bucketC (sub-CSR) + gemm1 (MFMA) — independent of each other
    combo_kernel<<<nb + g1grid, TB, 0, stream>>>(eout, bbas, bcnt, csr, offs, N, nb,
                                                 x16, W1T, a_src1, a_dst1, h1, alS1, alD1);
    // 5. layer-1 aggregation (+ fused al2 dots, hmid fp8)
    agg1_kernel<<<agrid, TB, 0, stream>>>(h1, csr, offs, alS1, alD1, b1,
                                          w2s, w2d, hmid, alS2, alD2, N);
    // 6. layer-2 aggregation in pre-projection space (fp8 gather)
    agg2_kernel<<<agrid, TB, 0, stream>>>(hmid, csr, offs, alS2, alD2, m16, N);
    // 7. layer-2 GEMM (MFMA) + bias
    gemm2_mfma<<<g2grid, TB, 0, stream>>>(m16, W2T, b2, (float*)d_out, N);
}